// Round 3
// baseline (270.746 us; speedup 1.0000x reference)
//
#include <hip/hip_runtime.h>

// SparseMaxPool via LDS slice composition.
// Valid offsets o=c-r: 0..15 (any r), odd 17..31 (r even),
// o%4==3 in 35..63 (r%4==0), o%8==7 in 71..127 (r%8==0).
// Window max via LDS doubling table: level-k base = 129*k - (2^k - 1),
// len = 129 - 2^k, 777 floats total.
//
// Structure: 512 persistent blocks (2/CU at ~68 KiB LDS), 8 slices each.
// The 64 KiB LDS tile is zeroed ONCE; every slice scatters its ~2548
// valid maxes over the same slots (zero slots never dirtied), then the
// tile streams to global as coalesced float4 nontemporal stores.
// => each output line written exactly once, near-zero VALU per element.

#define NN 128
#define SLICE_ELEMS (NN * NN)

typedef float f32x4 __attribute__((ext_vector_type(4)));   // native vector for nontemporal builtin

__device__ __forceinline__ void win_params(int o, int& lb, int& d2) {
    int w = o + 1;                 // window length
    int k = 31 - __clz(w);         // floor(log2(w)), w>=1
    int p2 = 1 << k;
    lb = 129 * k - (p2 - 1);       // level-k base (0,128,255,380,501,614,711,776)
    d2 = w - p2;                   // second-read offset
}

__global__ __launch_bounds__(256) void sparse_maxpool_kernel(
        const float* __restrict__ x, float* __restrict__ out,
        int n_slices, int spb) {
    __shared__ float tile[SLICE_ELEMS];   // composed slice (64 KiB)
    __shared__ float buf[784];            // doubling table (777 used)
    const int tid = threadIdx.x;

    // One-time zero of the tile: invalid positions stay 0 for all slices.
    f32x4 z = (f32x4)0.f;
    f32x4* __restrict__ t4 = reinterpret_cast<f32x4*>(tile);
    #pragma unroll
    for (int it = 0; it < 16; ++it)
        t4[it * 256 + tid] = z;

    int slice = blockIdx.x;               // stride gridDim.x over slices
    if (slice < n_slices && tid < NN)
        buf[tid] = x[(size_t)slice * NN + tid];
    __syncthreads();

    for (int s = 0; s < spb; ++s, slice += gridDim.x) {
        // ---- build doubling table levels 1..7 for current slice ----
        int base_prev = 0, base_cur = NN;
        #pragma unroll
        for (int k = 1; k <= 7; ++k) {
            int half = 1 << (k - 1);
            int len = (NN + 1) - (1 << k);
            if (tid < len)
                buf[base_cur + tid] = fmaxf(buf[base_prev + tid], buf[base_prev + tid + half]);
            __syncthreads();
            base_prev = base_cur;
            base_cur += len;
        }

        // ---- scatter valid entries into the LDS tile (tile[r*129 + o]) ----
        if (slice < n_slices) {
            {   // Group 1: o = 0..15, all rows. 16 offsets x 128 rows / 256 thr.
                int o = tid & 15, lb, d2;
                win_params(o, lb, d2);
                int r0 = tid >> 4;
                #pragma unroll
                for (int jj = 0; jj < 8; ++jj) {
                    int r = r0 + 16 * jj;
                    if (r + o < NN)
                        tile[r * 129 + o] = fmaxf(buf[lb + r], buf[lb + r + d2]);
                }
            }
            {   // Group 2: o = 17,19,..,31, r even.
                int o = 17 + 2 * (tid & 7), lb, d2;
                win_params(o, lb, d2);
                int r0 = 2 * (tid >> 3);
                #pragma unroll
                for (int jj = 0; jj < 2; ++jj) {
                    int r = r0 + 64 * jj;
                    if (r + o < NN)
                        tile[r * 129 + o] = fmaxf(buf[lb + r], buf[lb + r + d2]);
                }
            }
            {   // Group 3: o = 35,39,..,63, r%4==0.
                int o = 35 + 4 * (tid & 7), lb, d2;
                win_params(o, lb, d2);
                int r = 4 * (tid >> 3);
                if (r + o < NN)
                    tile[r * 129 + o] = fmaxf(buf[lb + r], buf[lb + r + d2]);
            }
            {   // Group 4: o = 71,79,..,127, r%8==0.
                int o = 71 + 8 * (tid & 7), lb, d2;
                win_params(o, lb, d2);
                int r = 8 * (tid >> 3);
                if (r + o < NN)
                    tile[r * 129 + o] = fmaxf(buf[lb + r], buf[lb + r + d2]);
            }
        }
        __syncthreads();

        // ---- stream the tile to global (single-visit, coalesced) ----
        // Prefetch next slice's x row under the store stream.
        int nslice = slice + gridDim.x;
        if (slice < n_slices) {
            f32x4* __restrict__ o4 =
                reinterpret_cast<f32x4*>(out + (size_t)slice * SLICE_ELEMS);
            #pragma unroll
            for (int it = 0; it < 16; ++it) {
                int idx = it * 256 + tid;
                __builtin_nontemporal_store(t4[idx], &o4[idx]);
            }
        }
        if (nslice < n_slices && tid < NN)
            buf[tid] = x[(size_t)nslice * NN + tid];
        __syncthreads();   // orders: stream reads < next scatter; x-load < next build
    }
}

extern "C" void kernel_launch(void* const* d_in, const int* in_sizes, int n_in,
                              void* d_out, int out_size, void* d_ws, size_t ws_size,
                              hipStream_t stream) {
    const float* x = (const float*)d_in[0];
    float* out = (float*)d_out;
    const int slices = in_sizes[0] / NN;   // 16*256 = 4096
    const int spb = 8;                     // slices per persistent block
    int nb = (slices + spb - 1) / spb;     // 512 blocks = 2 per CU
    sparse_maxpool_kernel<<<dim3(nb), dim3(256), 0, stream>>>(x, out, slices, spb);
}

// Round 4
// 261.800 us; speedup vs baseline: 1.0342x; 1.0342x over previous
//
#include <hip/hip_runtime.h>

// SparseMaxPool, single-visit full-line stores (R0 geometry) with split-level
// vectorized table reads.
// Valid offsets o=c-r: 0..15 (any r), odd 17..31 (r even), o%4==3 in 35..63
// (r%4==0), o%8==7 in 71..127 (r%8==0).
// Doubling table in LDS: level-k base lb(k)=129k-(2^k-1), len 129-2^k, 777 used.
// Per float4 (row r, cols c0..c0+3): w0=o0+1, k0=floor(log2(max(w0,1))),
// p=2^k0. Elements j with w_j<=2p use level k0: val=max(P_k0[r], buf[aV+j])
// where aV = lb0 + c0 + 1 - p (r-independent!). Elements with w_j>2p (only
// j>=s, s=2p-w0+1>=2) use level k0+1: val=max(VB0, VB[j-s+1]) where
// VB=buf[lb1+r ...]. Validity residue flags (o&7, r&7 const per thread,j)
// are hoisted out of the 16-iteration loop.

#define NN 128
#define SLICE_ELEMS (NN * NN)

typedef float f32x4 __attribute__((ext_vector_type(4)));

__device__ __forceinline__ bool ok_elem(int o, bool u1, bool u3, bool u7) {
    // class check: o<16 always ok; 16..31 needs u1; 32..63 u3; >=64 u7
    bool cls = (o < 16) ? true : (o < 32) ? u1 : (o < 64) ? u3 : u7;
    return (o >= 0) && cls;
}

__global__ __launch_bounds__(256) void sparse_maxpool_kernel(
        const float* __restrict__ x, float* __restrict__ out) {
    __shared__ float buf[1040];        // 777 table + pad (OOB-safe reads to ~906)
    const int tid = threadIdx.x;
    const int slice = blockIdx.x;      // b*256 + d, 4096 total

    // Level 0 = x slice; zero the pad so masked lanes read benign values.
    if (tid < NN) buf[tid] = x[(size_t)slice * NN + tid];
    for (int i = tid; i < 1040 - 777; i += 256) buf[777 + i] = 0.0f;
    __syncthreads();

    // Levels 1..7: P[k][i] = max(P[k-1][i], P[k-1][i + 2^{k-1}])
    int base_prev = 0, base_cur = NN;
    #pragma unroll
    for (int k = 1; k <= 7; ++k) {
        int half = 1 << (k - 1);
        int len = (NN + 1) - (1 << k);
        if (tid < len)
            buf[base_cur + tid] = fmaxf(buf[base_prev + tid], buf[base_prev + tid + half]);
        __syncthreads();
        base_prev = base_cur;
        base_cur += len;
    }

    const int c0 = (tid & 31) << 2;    // fixed columns per thread
    const int q  = tid >> 5;           // r = 8*it + q
    // Hoisted residue-class validity: o_j & 7 == (c0 + j - q) & 7, r & 7 == q & 7
    const bool qe1 = (q & 1) == 0, qe3 = (q & 3) == 0, qe7 = (q & 7) == 0;
    bool u1[4], u3[4], u7[4];
    #pragma unroll
    for (int j = 0; j < 4; ++j) {
        int rho = (c0 + j - q) & 7;
        u1[j] = ((rho & 1) == 1) && qe1;
        u3[j] = ((rho & 3) == 3) && qe3;
        u7[j] = (rho == 7)       && qe7;
    }

    f32x4* __restrict__ o4 = reinterpret_cast<f32x4*>(out + (size_t)slice * SLICE_ELEMS);

    #pragma unroll 4
    for (int it = 0; it < 16; ++it) {
        const int r  = (it << 3) + q;
        const int o0 = c0 - r;
        const int w0 = o0 + 1;
        const int wc = w0 < 1 ? 1 : w0;     // 1..125
        const int k0 = 31 - __clz(wc);      // 0..6
        const int p  = 1 << k0;
        const int lb0 = 129 * k0 - p + 1;   // level k0 base
        const int aA = lb0 + r;             // P_k0[r]
        const int aV = lb0 + c0 + 1 - p;    // run of level-k0 second operands (>=0)
        const int aB = lb0 + 129 - p + r;   // P_{k0+1}[r..r+2]
        const int s  = 2 * p - w0 + 1;      // first j on level k0+1 (s >= 2)

        const float A0  = buf[aA];
        const float VA0 = buf[aV],     VA1 = buf[aV + 1];
        const float VA2 = buf[aV + 2], VA3 = buf[aV + 3];
        const float VB0 = buf[aB],     VB1 = buf[aB + 1], VB2 = buf[aB + 2];

        const float e0 = fmaxf(A0, VA0);
        const float e1 = fmaxf(A0, VA1);
        const float e2 = (s == 2) ? fmaxf(VB0, VB1) : fmaxf(A0, VA2);
        const float e3 = (s <= 3) ? fmaxf(VB0, (s == 2) ? VB2 : VB1)
                                  : fmaxf(A0, VA3);

        f32x4 v;
        v.x = ok_elem(o0,     u1[0], u3[0], u7[0]) ? e0 : 0.0f;
        v.y = ok_elem(o0 + 1, u1[1], u3[1], u7[1]) ? e1 : 0.0f;
        v.z = ok_elem(o0 + 2, u1[2], u3[2], u7[2]) ? e2 : 0.0f;
        v.w = ok_elem(o0 + 3, u1[3], u3[3], u7[3]) ? e3 : 0.0f;

        o4[(it << 8) + tid] = v;
    }
}

extern "C" void kernel_launch(void* const* d_in, const int* in_sizes, int n_in,
                              void* d_out, int out_size, void* d_ws, size_t ws_size,
                              hipStream_t stream) {
    const float* x = (const float*)d_in[0];
    float* out = (float*)d_out;
    const int slices = in_sizes[0] / NN;   // 16*256 = 4096
    sparse_maxpool_kernel<<<dim3(slices), dim3(256), 0, stream>>>(x, out);
}